// Round 7
// baseline (297.052 us; speedup 1.0000x reference)
//
#include <hip/hip_runtime.h>
#include <math.h>

#define EMBED 128
#define BMAX 8192    // blockmax array size (score grid = N/16 = 6250 <= BMAX)
#define LDSPAD 136   // 128 + 8 bf16 pad -> 272 B row stride

typedef __attribute__((ext_vector_type(8))) short short8;
typedef __attribute__((ext_vector_type(4))) short short4v;
typedef __attribute__((ext_vector_type(4))) float floatx4;

__device__ __forceinline__ float fast_tanh2(float x) {     // 1 exp + 1 rcp, sign-safe
    float e = __expf(2.0f * x);                             // x<<0 -> 0 -> t=-1; x>>0 -> inf -> t=1
    return 1.0f - 2.0f * __builtin_amdgcn_rcpf(1.0f + e);
}

__device__ __forceinline__ unsigned short f2b(float f) {   // fp32 -> bf16 RNE
    union { float f; unsigned int u; } v; v.f = f;
    unsigned int r = v.u + 0x7FFFu + ((v.u >> 16) & 1u);
    return (unsigned short)(r >> 16);
}

__device__ __forceinline__ float b2f(short u) {
    union { float f; unsigned int i; } v;
    v.i = ((unsigned int)(unsigned short)u) << 16;
    return v.f;
}

// ---------------- K0: cast entity + rel tables to bf16 ----------------
__global__ __launch_bounds__(256) void k_cast(
    const float* __restrict__ ent, const float* __restrict__ rel,
    short* __restrict__ entb, short* __restrict__ relb, int ngE, int ngR)
{
    int stride = gridDim.x * 256;
    for (int g = blockIdx.x * 256 + threadIdx.x; g < ngE + ngR; g += stride) {
        const float4* src; short* dst;
        if (g < ngE) { src = (const float4*)ent + (size_t)g * 2; dst = entb + (size_t)g * 8; }
        else { int g2 = g - ngE; src = (const float4*)rel + (size_t)g2 * 2; dst = relb + (size_t)g2 * 8; }
        float4 a = src[0], b = src[1];
        short8 o;
        o[0] = (short)f2b(a.x); o[1] = (short)f2b(a.y); o[2] = (short)f2b(a.z); o[3] = (short)f2b(a.w);
        o[4] = (short)f2b(b.x); o[5] = (short)f2b(b.y); o[6] = (short)f2b(b.z); o[7] = (short)f2b(b.w);
        *(short8*)dst = o;
    }
}

// ---------------- K1: head histogram ----------------
__global__ __launch_bounds__(256) void k_hist(
    const int* __restrict__ heads, int* __restrict__ cnt, int E)
{
    int stride = gridDim.x * 256;
    for (int e = blockIdx.x * 256 + threadIdx.x; e < E; e += stride)
        atomicAdd(cnt + heads[e], 1);
}

// ---------------- K2a/b/c: two-level scan ----------------
__global__ __launch_bounds__(1024) void k_scan1(
    const int* __restrict__ cnt, int* __restrict__ offs,
    int* __restrict__ bsum, int N)
{
    __shared__ int buf[1024];
    int i = blockIdx.x * 1024 + threadIdx.x;
    int v = (i < N) ? cnt[i] : 0;
    buf[threadIdx.x] = v;
    __syncthreads();
    for (int off = 1; off < 1024; off <<= 1) {
        int x = (threadIdx.x >= (unsigned)off) ? buf[threadIdx.x - off] : 0;
        __syncthreads();
        buf[threadIdx.x] += x;
        __syncthreads();
    }
    if (i < N) offs[i] = buf[threadIdx.x] - v;
    if (threadIdx.x == 1023) bsum[blockIdx.x] = buf[1023];
}

__global__ __launch_bounds__(1024) void k_scan2(int* __restrict__ bsum, int nb)
{
    __shared__ int buf[1024];
    int v = (threadIdx.x < (unsigned)nb) ? bsum[threadIdx.x] : 0;
    buf[threadIdx.x] = v;
    __syncthreads();
    for (int off = 1; off < 1024; off <<= 1) {
        int x = (threadIdx.x >= (unsigned)off) ? buf[threadIdx.x - off] : 0;
        __syncthreads();
        buf[threadIdx.x] += x;
        __syncthreads();
    }
    if (threadIdx.x < (unsigned)nb) bsum[threadIdx.x] = buf[threadIdx.x] - v;
}

__global__ __launch_bounds__(256) void k_scan3(
    int* __restrict__ offs, const int* __restrict__ bsum,
    int* __restrict__ cursor, int N)
{
    int i = blockIdx.x * 256 + threadIdx.x;
    if (i < N) {
        int o = offs[i] + bsum[i >> 10];
        offs[i] = o;
        cursor[i] = o;
    }
}

// ---------------- K3: CSR slot-fill: (tail, rel) per slot, head-sorted ----------------
__global__ __launch_bounds__(256) void k_csr(
    const int* __restrict__ heads, const int* __restrict__ rels,
    const int* __restrict__ tails, int* __restrict__ cursor,
    int* __restrict__ tailid, int* __restrict__ relid, int E)
{
    int e = blockIdx.x * 256 + threadIdx.x;
    if (e >= E) return;
    int pos = atomicAdd(cursor + heads[e], 1);
    tailid[pos] = tails[e];
    relid[pos]  = rels[e];
}

// ---------------- K4: CSR-ordered score + global max ----------------
// One 16-lane group per head: head row loaded once (sequential across groups).
__global__ __launch_bounds__(256) void k_score_csr(
    const short* __restrict__ entb, const short* __restrict__ relb,
    const int* __restrict__ offs, const int* __restrict__ cnt,
    const int* __restrict__ tailid, const int* __restrict__ relid,
    float* __restrict__ score, float* __restrict__ blockmax, int N)
{
    const int lane = threadIdx.x & 15;
    int head = blockIdx.x * 16 + (threadIdx.x >> 4);
    float lmax = -INFINITY;
    if (head < N) {
        int start = offs[head];
        int c     = cnt[head];
        short8 hh = *((const short8*)(entb + (size_t)head * EMBED) + lane);
        float hf[8];
        #pragma unroll
        for (int i = 0; i < 8; ++i) hf[i] = b2f(hh[i]);
        for (int base = 0; base < c; base += 16) {
            int rem = c - base;
            int m   = rem < 16 ? rem : 16;
            int tv = 0, rv = 0;
            if (lane < m) { tv = tailid[start + base + lane]; rv = relid[start + base + lane]; }
            for (int j = 0; j < m; ++j) {
                int t = __shfl(tv, j, 16);
                int r = __shfl(rv, j, 16);
                short8 vt = *((const short8*)(entb + (size_t)t * EMBED) + lane);
                short8 vr = *((const short8*)(relb + (size_t)r * EMBED) + lane);
                float s = 0.f;
                #pragma unroll
                for (int i = 0; i < 8; ++i)
                    s += b2f(vt[i]) * fast_tanh2(hf[i] + b2f(vr[i]));
                s += __shfl_xor(s, 1, 16);
                s += __shfl_xor(s, 2, 16);
                s += __shfl_xor(s, 4, 16);
                s += __shfl_xor(s, 8, 16);
                if (lane == 0) score[start + base + j] = s;
                lmax = fmaxf(lmax, s);
            }
        }
    }
    __shared__ float smax[256];
    smax[threadIdx.x] = lmax;
    __syncthreads();
    for (int off = 128; off > 0; off >>= 1) {
        if ((int)threadIdx.x < off)
            smax[threadIdx.x] = fmaxf(smax[threadIdx.x], smax[threadIdx.x + off]);
        __syncthreads();
    }
    if (threadIdx.x == 0) blockmax[blockIdx.x] = smax[0];
}

// ---------------- K4b: reduce blockmax -> M ----------------
__global__ __launch_bounds__(256) void k_maxred(
    const float* __restrict__ blockmax, float* __restrict__ Mout, int n)
{
    __shared__ float smax[256];
    float m = -INFINITY;
    for (int i = threadIdx.x; i < n; i += 256) m = fmaxf(m, blockmax[i]);
    smax[threadIdx.x] = m;
    __syncthreads();
    for (int off = 128; off > 0; off >>= 1) {
        if ((int)threadIdx.x < off)
            smax[threadIdx.x] = fmaxf(smax[threadIdx.x], smax[threadIdx.x + off]);
        __syncthreads();
    }
    if (threadIdx.x == 0) Mout[0] = smax[0];
}

// ---------------- K5: fused exp + per-head gather + x = ent + agg, bf16 out ----------------
__global__ __launch_bounds__(256) void k_aggx(
    const short* __restrict__ entb, const int* __restrict__ offs,
    const int* __restrict__ cnt, const float* __restrict__ score,
    const int* __restrict__ tailid, const float* __restrict__ Mptr,
    short* __restrict__ xb, int N)
{
    const int lane = threadIdx.x & 15;
    int head = blockIdx.x * 16 + (threadIdx.x >> 4);
    if (head >= N) return;
    int start = offs[head];
    int c     = cnt[head];
    float M   = Mptr[0];
    short8 hh = *((const short8*)(entb + (size_t)head * EMBED) + lane);
    float acc[8] = {0,0,0,0,0,0,0,0};
    float denom = 0.f;
    for (int base = 0; base < c; base += 16) {
        int rem = c - base;
        int m   = rem < 16 ? rem : 16;
        float pv = 0.f; int tv = 0;
        if (lane < m) {
            pv = __expf(score[start + base + lane] - M);
            tv = tailid[start + base + lane];
        }
        for (int j = 0; j < m; ++j) {
            float p = __shfl(pv, j, 16);
            int   t = __shfl(tv, j, 16);
            short8 v = *((const short8*)(entb + (size_t)t * EMBED) + lane);
            #pragma unroll
            for (int q = 0; q < 8; ++q) acc[q] += p * b2f(v[q]);
            denom += p;
        }
    }
    float inv = 1.0f / (denom + 1e-10f);
    short8 o;
    #pragma unroll
    for (int q = 0; q < 8; ++q) o[q] = (short)f2b(b2f(hh[q]) + acc[q] * inv);
    *((short8*)(xb + (size_t)head * EMBED) + lane) = o;
}

// ---------------- K6: out = leaky_relu(xb @ W^T) via bf16 MFMA ----------------
__global__ __launch_bounds__(256) void k_gemm_b(
    const short* __restrict__ xb, const float* __restrict__ W,
    float* __restrict__ out, int N)
{
    __shared__ short xs[128 * LDSPAD];
    __shared__ short ws[128 * LDSPAD];
    const int tid = threadIdx.x;
    const int n0  = blockIdx.x * 128;

    // stage W (fp32 -> bf16): 4096 float4, 16 per thread
    #pragma unroll
    for (int it = 0; it < 16; ++it) {
        int f4 = it * 256 + tid;
        int row = f4 >> 5, col4 = f4 & 31;
        float4 v = ((const float4*)W)[f4];
        short4v b; b[0] = (short)f2b(v.x); b[1] = (short)f2b(v.y);
                   b[2] = (short)f2b(v.z); b[3] = (short)f2b(v.w);
        *(short4v*)(ws + row * LDSPAD + col4 * 4) = b;
    }
    // stage xb tile: 2048 short8 chunks, 8 per thread
    #pragma unroll
    for (int it = 0; it < 8; ++it) {
        int ch = it * 256 + tid;
        int row = ch >> 4, col8 = ch & 15;
        int g = n0 + row;
        short8 v = {0,0,0,0,0,0,0,0};
        if (g < N) v = *((const short8*)(xb + (size_t)g * EMBED) + col8);
        *(short8*)(xs + row * LDSPAD + col8 * 8) = v;
    }
    __syncthreads();

    const int wv   = tid >> 6;
    const int lane = tid & 63;
    const int n16  = lane & 15;
    const int quad = lane >> 4;

    floatx4 acc[2][8];
    #pragma unroll
    for (int rt = 0; rt < 2; ++rt)
        #pragma unroll
        for (int jt = 0; jt < 8; ++jt)
            acc[rt][jt] = (floatx4){0.f, 0.f, 0.f, 0.f};

    #pragma unroll
    for (int kc = 0; kc < 4; ++kc) {
        int koff = kc * 32 + quad * 8;
        short8 a0 = *(const short8*)(xs + (wv * 32      + n16) * LDSPAD + koff);
        short8 a1 = *(const short8*)(xs + (wv * 32 + 16 + n16) * LDSPAD + koff);
        #pragma unroll
        for (int jt = 0; jt < 8; ++jt) {
            short8 b = *(const short8*)(ws + (jt * 16 + n16) * LDSPAD + koff);
            acc[0][jt] = __builtin_amdgcn_mfma_f32_16x16x32_bf16(a0, b, acc[0][jt], 0, 0, 0);
            acc[1][jt] = __builtin_amdgcn_mfma_f32_16x16x32_bf16(a1, b, acc[1][jt], 0, 0, 0);
        }
    }

    #pragma unroll
    for (int rt = 0; rt < 2; ++rt) {
        int rowbase = n0 + wv * 32 + rt * 16 + quad * 4;
        #pragma unroll
        for (int r = 0; r < 4; ++r) {
            int grow = rowbase + r;
            if (grow < N) {
                float* o = out + (size_t)grow * EMBED + n16;
                #pragma unroll
                for (int jt = 0; jt < 8; ++jt) {
                    float v = acc[rt][jt][r];
                    o[jt * 16] = (v > 0.f) ? v : 0.2f * v;
                }
            }
        }
    }
}

extern "C" void kernel_launch(void* const* d_in, const int* in_sizes, int n_in,
                              void* d_out, int out_size, void* d_ws, size_t ws_size,
                              hipStream_t stream)
{
    const float* ent   = (const float*)d_in[0];   // entity_emb  [N,128] fp32
    const float* rel   = (const float*)d_in[1];   // rel_embed   [64,128] fp32
    const float* W     = (const float*)d_in[2];   // W           [128,128] fp32
    const int*   heads = (const int*)d_in[3];
    const int*   rels  = (const int*)d_in[4];
    const int*   tails = (const int*)d_in[5];
    const int E = in_sizes[3];
    const int N = in_sizes[0] / EMBED;
    const int R = in_sizes[1] / EMBED;
    float* out = (float*)d_out;

    // ws layout: xb[N*128]s | score[E]f | tailid[E]i | relid[E]i | cnt[N]i | offs[N]i |
    //            cursor[N]i | blockmax[BMAX]f | M[1]f | bsum[1024]i | entb[N*128]s | relb[R*128]s
    short* xb       = (short*)d_ws;
    float* score    = (float*)(xb + (size_t)N * EMBED);
    int*   tailid   = (int*)(score + E);
    int*   relid    = tailid + E;
    int*   cnt      = relid + E;
    int*   offs     = cnt + N;
    int*   cursor   = offs + N;
    float* blockmax = (float*)(cursor + N);
    float* Mval     = blockmax + BMAX;
    int*   bsum     = (int*)(Mval + 1);
    short* entb     = (short*)(bsum + 1024);
    short* relb     = entb + (size_t)N * EMBED;

    const int nb  = (N + 1023) >> 10;       // scan blocks
    const int ngh = (N + 15) / 16;          // per-head group blocks

    hipMemsetAsync(cnt, 0, (size_t)N * sizeof(int), stream);

    int ngE = N * EMBED / 8, ngR = R * EMBED / 8;
    k_cast<<<2048, 256, 0, stream>>>(ent, rel, entb, relb, ngE, ngR);
    k_hist<<<1024, 256, 0, stream>>>(heads, cnt, E);
    k_scan1<<<nb, 1024, 0, stream>>>(cnt, offs, bsum, N);
    k_scan2<<<1, 1024, 0, stream>>>(bsum, nb);
    k_scan3<<<(N + 255) / 256, 256, 0, stream>>>(offs, bsum, cursor, N);
    k_csr<<<(E + 255) / 256, 256, 0, stream>>>(heads, rels, tails, cursor, tailid, relid, E);
    k_score_csr<<<ngh, 256, 0, stream>>>(entb, relb, offs, cnt, tailid, relid, score, blockmax, N);
    k_maxred<<<1, 256, 0, stream>>>(blockmax, Mval, ngh);
    k_aggx<<<ngh, 256, 0, stream>>>(entb, offs, cnt, score, tailid, Mval, xb, N);
    k_gemm_b<<<(N + 127) / 128, 256, 0, stream>>>(xb, W, out, N);
}

// Round 8
// 259.593 us; speedup vs baseline: 1.1443x; 1.1443x over previous
//
#include <hip/hip_runtime.h>
#include <math.h>

#define EMBED 128
#define BMAX 8192    // blockmax array (fused grid = ceil(N/16) = 6250 <= BMAX)
#define LDSPAD 136   // 128 + 8 bf16 pad -> 272 B row stride

typedef __attribute__((ext_vector_type(8))) short short8;
typedef __attribute__((ext_vector_type(4))) short short4v;
typedef __attribute__((ext_vector_type(4))) float floatx4;

__device__ __forceinline__ float fast_tanh2(float x) {     // 1 exp + 1 rcp, sign-safe
    float e = __expf(2.0f * x);                             // x<<0 -> 0 -> -1; x>>0 -> inf -> 1
    return 1.0f - 2.0f * __builtin_amdgcn_rcpf(1.0f + e);
}

__device__ __forceinline__ unsigned short f2b(float f) {   // fp32 -> bf16 RNE
    union { float f; unsigned int u; } v; v.f = f;
    unsigned int r = v.u + 0x7FFFu + ((v.u >> 16) & 1u);
    return (unsigned short)(r >> 16);
}

__device__ __forceinline__ float b2f(short u) {
    union { float f; unsigned int i; } v;
    v.i = ((unsigned int)(unsigned short)u) << 16;
    return v.f;
}

// ---------------- K0: cast tables to bf16 + head histogram ----------------
__global__ __launch_bounds__(256) void k_cast_hist(
    const float* __restrict__ ent, const float* __restrict__ rel,
    short* __restrict__ entb, short* __restrict__ relb,
    const int* __restrict__ heads, int* __restrict__ cnt,
    int ngE, int ngR, int E)
{
    int stride = gridDim.x * 256;
    for (int g = blockIdx.x * 256 + threadIdx.x; g < ngE + ngR; g += stride) {
        const float4* src; short* dst;
        if (g < ngE) { src = (const float4*)ent + (size_t)g * 2; dst = entb + (size_t)g * 8; }
        else { int g2 = g - ngE; src = (const float4*)rel + (size_t)g2 * 2; dst = relb + (size_t)g2 * 8; }
        float4 a = src[0], b = src[1];
        short8 o;
        o[0] = (short)f2b(a.x); o[1] = (short)f2b(a.y); o[2] = (short)f2b(a.z); o[3] = (short)f2b(a.w);
        o[4] = (short)f2b(b.x); o[5] = (short)f2b(b.y); o[6] = (short)f2b(b.z); o[7] = (short)f2b(b.w);
        *(short8*)dst = o;
    }
    for (int e = blockIdx.x * 256 + threadIdx.x; e < E; e += stride)
        atomicAdd(cnt + heads[e], 1);
}

// ---------------- K1a/b/c: two-level scan ----------------
__global__ __launch_bounds__(1024) void k_scan1(
    const int* __restrict__ cnt, int* __restrict__ offs,
    int* __restrict__ bsum, int N)
{
    __shared__ int buf[1024];
    int i = blockIdx.x * 1024 + threadIdx.x;
    int v = (i < N) ? cnt[i] : 0;
    buf[threadIdx.x] = v;
    __syncthreads();
    for (int off = 1; off < 1024; off <<= 1) {
        int x = (threadIdx.x >= (unsigned)off) ? buf[threadIdx.x - off] : 0;
        __syncthreads();
        buf[threadIdx.x] += x;
        __syncthreads();
    }
    if (i < N) offs[i] = buf[threadIdx.x] - v;
    if (threadIdx.x == 1023) bsum[blockIdx.x] = buf[1023];
}

__global__ __launch_bounds__(1024) void k_scan2(int* __restrict__ bsum, int nb)
{
    __shared__ int buf[1024];
    int v = (threadIdx.x < (unsigned)nb) ? bsum[threadIdx.x] : 0;
    buf[threadIdx.x] = v;
    __syncthreads();
    for (int off = 1; off < 1024; off <<= 1) {
        int x = (threadIdx.x >= (unsigned)off) ? buf[threadIdx.x - off] : 0;
        __syncthreads();
        buf[threadIdx.x] += x;
        __syncthreads();
    }
    if (threadIdx.x < (unsigned)nb) bsum[threadIdx.x] = buf[threadIdx.x] - v;
}

__global__ __launch_bounds__(256) void k_scan3(
    int* __restrict__ offs, const int* __restrict__ bsum,
    int* __restrict__ cursor, int N)
{
    int i = blockIdx.x * 256 + threadIdx.x;
    if (i < N) {
        int o = offs[i] + bsum[i >> 10];
        offs[i] = o;
        cursor[i] = o;
    }
}

// ---------------- K2: CSR slot-fill: packed (tail, rel) per slot ----------------
__global__ __launch_bounds__(256) void k_csr(
    const int* __restrict__ heads, const int* __restrict__ rels,
    const int* __restrict__ tails, int* __restrict__ cursor,
    int2* __restrict__ tr, int E)
{
    int e = blockIdx.x * 256 + threadIdx.x;
    if (e >= E) return;
    int pos = atomicAdd(cursor + heads[e], 1);
    tr[pos] = make_int2(tails[e], rels[e]);
}

// ---------------- K3: fused score + online-softmax aggregate ----------------
// 16 lanes per head. One tail-row gather serves both the tanh-dot and the
// weighted accumulate. Writes acc (bf16, unnormalized), per-head (m, l), blockmax.
__global__ __launch_bounds__(256) void k_fused(
    const short* __restrict__ entb, const short* __restrict__ relb,
    const int* __restrict__ offs, const int* __restrict__ cnt,
    const int2* __restrict__ tr,
    short* __restrict__ accb, float* __restrict__ mh, float* __restrict__ lh,
    float* __restrict__ blockmax, int N, int R)
{
    __shared__ short rl[64 * EMBED];   // 16 KB rel table cache
    const int tid = threadIdx.x;
    if (R <= 64) {
        int nch = R * 16;
        for (int i = tid; i < nch; i += 256)
            ((short8*)rl)[i] = ((const short8*)relb)[i];
    }
    __syncthreads();
    const short* relsrc = (R <= 64) ? (const short*)rl : relb;

    const int lane = tid & 15;
    int head = blockIdx.x * 16 + (tid >> 4);
    float m = -INFINITY;
    if (head < N) {
        int start = offs[head];
        int c     = cnt[head];
        short8 hh = *((const short8*)(entb + (size_t)head * EMBED) + lane);
        float hf[8];
        #pragma unroll
        for (int i = 0; i < 8; ++i) hf[i] = b2f(hh[i]);
        float l = 0.f;
        float acc[8] = {0,0,0,0,0,0,0,0};
        for (int base = 0; base < c; base += 16) {
            int rem = c - base;
            int mm  = rem < 16 ? rem : 16;
            int2 trv = make_int2(0, 0);
            if (lane < mm) trv = tr[start + base + lane];
            for (int j = 0; j < mm; ++j) {
                int t = __shfl(trv.x, j, 16);
                int r = __shfl(trv.y, j, 16);
                short8 vt = *((const short8*)(entb + (size_t)t * EMBED) + lane);
                short8 vr = *((const short8*)(relsrc + (size_t)r * EMBED) + lane);
                float s = 0.f;
                #pragma unroll
                for (int i = 0; i < 8; ++i)
                    s += b2f(vt[i]) * fast_tanh2(hf[i] + b2f(vr[i]));
                s += __shfl_xor(s, 1, 16);
                s += __shfl_xor(s, 2, 16);
                s += __shfl_xor(s, 4, 16);
                s += __shfl_xor(s, 8, 16);
                float mn    = fmaxf(m, s);
                float alpha = __expf(m - mn);     // m=-inf first edge -> 0
                float p     = __expf(s - mn);
                l = l * alpha + p;
                #pragma unroll
                for (int q = 0; q < 8; ++q)
                    acc[q] = acc[q] * alpha + p * b2f(vt[q]);
                m = mn;
            }
        }
        short8 o;
        #pragma unroll
        for (int q = 0; q < 8; ++q) o[q] = (short)f2b(acc[q]);
        *((short8*)(accb + (size_t)head * EMBED) + lane) = o;
        if (lane == 0) { mh[head] = m; lh[head] = l; }
    }
    __shared__ float smax[256];
    smax[tid] = m;
    __syncthreads();
    for (int off = 128; off > 0; off >>= 1) {
        if (tid < off) smax[tid] = fmaxf(smax[tid], smax[tid + off]);
        __syncthreads();
    }
    if (tid == 0) blockmax[blockIdx.x] = smax[0];
}

// ---------------- K3b: reduce blockmax -> M ----------------
__global__ __launch_bounds__(256) void k_maxred(
    const float* __restrict__ blockmax, float* __restrict__ Mout, int n)
{
    __shared__ float smax[256];
    float m = -INFINITY;
    for (int i = threadIdx.x; i < n; i += 256) m = fmaxf(m, blockmax[i]);
    smax[threadIdx.x] = m;
    __syncthreads();
    for (int off = 128; off > 0; off >>= 1) {
        if ((int)threadIdx.x < off)
            smax[threadIdx.x] = fmaxf(smax[threadIdx.x], smax[threadIdx.x + off]);
        __syncthreads();
    }
    if (threadIdx.x == 0) Mout[0] = smax[0];
}

// ---------------- K4: fused normalize + x = ent + agg + bf16 MFMA GEMM ----------------
// x[g] = entb[g] + accb[g] / (lh[g] + 1e-10*exp(M - mh[g])); out = leaky_relu(x @ W^T).
__global__ __launch_bounds__(256) void k_gemm_f(
    const short* __restrict__ entb, const short* __restrict__ accb,
    const float* __restrict__ mh, const float* __restrict__ lh,
    const float* __restrict__ Mptr, const float* __restrict__ W,
    float* __restrict__ out, int N)
{
    __shared__ short xs[128 * LDSPAD];
    __shared__ short ws[128 * LDSPAD];
    const int tid = threadIdx.x;
    const int n0  = blockIdx.x * 128;
    const float M = Mptr[0];

    // stage W (fp32 -> bf16): 4096 float4, 16 per thread
    #pragma unroll
    for (int it = 0; it < 16; ++it) {
        int f4 = it * 256 + tid;
        int row = f4 >> 5, col4 = f4 & 31;
        float4 v = ((const float4*)W)[f4];
        short4v b; b[0] = (short)f2b(v.x); b[1] = (short)f2b(v.y);
                   b[2] = (short)f2b(v.z); b[3] = (short)f2b(v.w);
        *(short4v*)(ws + row * LDSPAD + col4 * 4) = b;
    }
    // stage x = ent + acc*inv: 2048 short8 chunks, 8 per thread
    #pragma unroll
    for (int it = 0; it < 8; ++it) {
        int ch = it * 256 + tid;
        int row = ch >> 4, col8 = ch & 15;
        int g = n0 + row;
        short8 v = {0,0,0,0,0,0,0,0};
        if (g < N) {
            float inv = 1.0f / (lh[g] + 1e-10f * __expf(M - mh[g]));  // inf -> 0 (degenerate head)
            short8 e8 = *((const short8*)(entb + (size_t)g * EMBED) + col8);
            short8 a8 = *((const short8*)(accb + (size_t)g * EMBED) + col8);
            #pragma unroll
            for (int q = 0; q < 8; ++q)
                v[q] = (short)f2b(b2f(e8[q]) + b2f(a8[q]) * inv);
        }
        *(short8*)(xs + row * LDSPAD + col8 * 8) = v;
    }
    __syncthreads();

    const int wv   = tid >> 6;
    const int lane = tid & 63;
    const int n16  = lane & 15;
    const int quad = lane >> 4;

    floatx4 acc[2][8];
    #pragma unroll
    for (int rt = 0; rt < 2; ++rt)
        #pragma unroll
        for (int jt = 0; jt < 8; ++jt)
            acc[rt][jt] = (floatx4){0.f, 0.f, 0.f, 0.f};

    #pragma unroll
    for (int kc = 0; kc < 4; ++kc) {
        int koff = kc * 32 + quad * 8;
        short8 a0 = *(const short8*)(xs + (wv * 32      + n16) * LDSPAD + koff);
        short8 a1 = *(const short8*)(xs + (wv * 32 + 16 + n16) * LDSPAD + koff);
        #pragma unroll
        for (int jt = 0; jt < 8; ++jt) {
            short8 b = *(const short8*)(ws + (jt * 16 + n16) * LDSPAD + koff);
            acc[0][jt] = __builtin_amdgcn_mfma_f32_16x16x32_bf16(a0, b, acc[0][jt], 0, 0, 0);
            acc[1][jt] = __builtin_amdgcn_mfma_f32_16x16x32_bf16(a1, b, acc[1][jt], 0, 0, 0);
        }
    }

    #pragma unroll
    for (int rt = 0; rt < 2; ++rt) {
        int rowbase = n0 + wv * 32 + rt * 16 + quad * 4;
        #pragma unroll
        for (int r = 0; r < 4; ++r) {
            int grow = rowbase + r;
            if (grow < N) {
                float* o = out + (size_t)grow * EMBED + n16;
                #pragma unroll
                for (int jt = 0; jt < 8; ++jt) {
                    float v = acc[rt][jt][r];
                    o[jt * 16] = (v > 0.f) ? v : 0.2f * v;
                }
            }
        }
    }
}

extern "C" void kernel_launch(void* const* d_in, const int* in_sizes, int n_in,
                              void* d_out, int out_size, void* d_ws, size_t ws_size,
                              hipStream_t stream)
{
    const float* ent   = (const float*)d_in[0];   // entity_emb  [N,128] fp32
    const float* rel   = (const float*)d_in[1];   // rel_embed   [R,128] fp32
    const float* W     = (const float*)d_in[2];   // W           [128,128] fp32
    const int*   heads = (const int*)d_in[3];
    const int*   rels  = (const int*)d_in[4];
    const int*   tails = (const int*)d_in[5];
    const int E = in_sizes[3];
    const int N = in_sizes[0] / EMBED;
    const int R = in_sizes[1] / EMBED;
    float* out = (float*)d_out;

    // ws layout: accb[N*128]s | mh[N]f | lh[N]f | tr[E]int2 | cnt[N]i | offs[N]i |
    //            cursor[N]i | blockmax[BMAX]f | M[1]f | bsum[1024]i | entb[N*128]s | relb[R*128]s
    short* accb     = (short*)d_ws;
    float* mh       = (float*)(accb + (size_t)N * EMBED);
    float* lh       = mh + N;
    int2*  tr       = (int2*)(lh + N);
    int*   cnt      = (int*)(tr + E);
    int*   offs     = cnt + N;
    int*   cursor   = offs + N;
    float* blockmax = (float*)(cursor + N);
    float* Mval     = blockmax + BMAX;
    int*   bsum     = (int*)(Mval + 1);
    short* entb     = (short*)(bsum + 1024);
    short* relb     = entb + (size_t)N * EMBED;

    const int nb  = (N + 1023) >> 10;       // scan blocks
    const int ngh = (N + 15) / 16;          // per-head group blocks

    hipMemsetAsync(cnt, 0, (size_t)N * sizeof(int), stream);

    int ngE = N * EMBED / 8, ngR = R * EMBED / 8;
    k_cast_hist<<<2048, 256, 0, stream>>>(ent, rel, entb, relb, heads, cnt, ngE, ngR, E);
    k_scan1<<<nb, 1024, 0, stream>>>(cnt, offs, bsum, N);
    k_scan2<<<1, 1024, 0, stream>>>(bsum, nb);
    k_scan3<<<(N + 255) / 256, 256, 0, stream>>>(offs, bsum, cursor, N);
    k_csr<<<(E + 255) / 256, 256, 0, stream>>>(heads, rels, tails, cursor, tr, E);
    k_fused<<<ngh, 256, 0, stream>>>(entb, relb, offs, cnt, tr, accb, mh, lh, blockmax, N, R);
    k_maxred<<<1, 256, 0, stream>>>(blockmax, Mval, ngh);
    k_gemm_f<<<(N + 127) / 128, 256, 0, stream>>>(entb, accb, mh, lh, Mval, W, out, N);
}